// Round 1
// baseline (244.924 us; speedup 1.0000x reference)
//
#include <hip/hip_runtime.h>

#define BB 4
#define NN 4096
#define EE 1024
#define FIN 128
#define FOUT 128
#define FE 64
#define CAP 33
#define LSTRIDE 34

typedef unsigned short u16;
typedef unsigned long long u64;

// ---------------- K1: HePe[b,e] = dot(edge[b,e,:], edge_weight) ----------------
__global__ __launch_bounds__(256) void k_hepe(const float* __restrict__ edge,
                                              const float* __restrict__ ew,
                                              float* __restrict__ hepe) {
    int lane = threadIdx.x & 63;
    int wid  = threadIdx.x >> 6;
    int row  = blockIdx.x * 4 + wid;            // b*E + e
    float v = edge[(size_t)row * FE + lane] * ew[lane];
#pragma unroll
    for (int d = 32; d >= 1; d >>= 1) v += __shfl_xor(v, d, 64);
    if (lane == 0) hepe[row] = v;
}

// ---------------- K2: dinv[b,n] = 1/sqrt(D[b,n,n]) ----------------
__global__ __launch_bounds__(256) void k_dinv(const float* __restrict__ D,
                                              float* __restrict__ dinv) {
    int t = blockIdx.x * 256 + threadIdx.x;     // b*N + n
    int b = t >> 12, n = t & (NN - 1);
    float v = D[((size_t)b * NN + n) * NN + n];
    dinv[t] = (v != 0.0f) ? (1.0f / sqrtf(v)) : 0.0f;
}

// ---------------- K3: per-node sorted edge list from T ----------------
__global__ __launch_bounds__(256) void k_lists(const float* __restrict__ T,
                                               u16* __restrict__ lists) {
    int lane = threadIdx.x & 63;
    int wid  = threadIdx.x >> 6;
    int row  = blockIdx.x * 4 + wid;            // b*N + n
    const float4* rowT = (const float4*)(T + (size_t)row * EE);
    u16* L = lists + (size_t)row * LSTRIDE;
    int base = 0;
#pragma unroll
    for (int i = 0; i < 4; i++) {
        float4 tv = rowT[i * 64 + lane];
        float vs[4] = {tv.x, tv.y, tv.z, tv.w};
        int c = (tv.x != 0.f) + (tv.y != 0.f) + (tv.z != 0.f) + (tv.w != 0.f);
        int x = c;
#pragma unroll
        for (int d = 1; d < 64; d <<= 1) {
            int o = __shfl_up(x, d, 64);
            if (lane >= d) x += o;
        }
        int tot = __shfl(x, 63, 64);
        int pos = base + x - c;
#pragma unroll
        for (int s = 0; s < 4; s++) {
            if (vs[s] != 0.f) {
                if (pos < CAP) L[1 + pos] = (u16)((i * 64 + lane) * 4 + s);
                pos++;
            }
        }
        base += tot;
    }
    if (lane == 0) L[0] = (u16)(base < CAP ? base : CAP);
}

// ---------------- K4: out1[b,n,:] = sum_m A~[n,m]*S[n,m]*node[m,:] ----------------
__global__ __launch_bounds__(256) void k_main(const float* __restrict__ A,
                                              const float* __restrict__ node,
                                              const float* __restrict__ hepe,
                                              const float* __restrict__ dinv,
                                              const u16* __restrict__ lists,
                                              float* __restrict__ out1) {
    __shared__ u16   sList[4][CAP + 1];
    __shared__ float sVals[4][CAP + 1];
    int lane = threadIdx.x & 63;
    int wid  = threadIdx.x >> 6;
    int row  = blockIdx.x * 4 + wid;            // b*N + n
    int b = row >> 12, n = row & (NN - 1);

    const u16* L = lists + (size_t)row * LSTRIDE;
    int cn = L[0];
    float hv = 0.f;
    if (lane < cn) {
        int e = L[1 + lane];
        sList[wid][lane] = (u16)e;
        hv = hepe[(b << 10) + e];
        sVals[wid][lane] = hv;
    }
    float sd = hv;                               // S[n,n] = sum of own HePe
#pragma unroll
    for (int d = 32; d >= 1; d >>= 1) sd += __shfl_xor(sd, d, 64);
    __syncthreads();

    const float4* rowA  = (const float4*)(A + (size_t)row * NN);
    const float2* node2 = (const float2*)node;
    float2 acc = make_float2(0.f, 0.f);

    for (int i = 0; i < 16; i++) {
        float4 av = rowA[i * 64 + lane];
        int m0 = (i * 64 + lane) * 4;
        float avv[4] = {av.x, av.y, av.z, av.w};
        float w[4];
#pragma unroll
        for (int s = 0; s < 4; s++) {
            int m = m0 + s;
            float a = avv[s];
            if (m == n) a += 1.0f;               // A = node_adj + I
            float wv = 0.f;
            if (a != 0.f) {
                float sv;
                if (m == n) {
                    sv = sd;
                } else if (cn == 0) {
                    sv = 0.f;
                } else {
                    const u16* Lm = lists + (size_t)((b << 12) + m) * LSTRIDE;
                    int cm = Lm[0];
                    sv = 0.f;
                    if (cm > 0) {
                        int ii = 0, jj = 0;
                        u16 en = sList[wid][0];
                        u16 em = Lm[1];
                        while (true) {
                            if (en == em) {
                                sv += sVals[wid][ii];
                                ii++; jj++;
                                if (ii >= cn || jj >= cm) break;
                                en = sList[wid][ii]; em = Lm[1 + jj];
                            } else if (en < em) {
                                ii++; if (ii >= cn) break; en = sList[wid][ii];
                            } else {
                                jj++; if (jj >= cm) break; em = Lm[1 + jj];
                            }
                        }
                    }
                }
                if (sv != 0.f) wv = a * sv * dinv[(b << 12) + m];
            }
            w[s] = wv;
        }
#pragma unroll
        for (int s = 0; s < 4; s++) {
            u64 mask = __ballot(w[s] != 0.f);
            while (mask) {
                int src = __ffsll(mask) - 1;
                mask &= mask - 1;
                float wb = __shfl(w[s], src, 64);
                int mb = (i * 64 + src) * 4 + s;
                float2 nv = node2[((size_t)((b << 12) + mb)) * 64 + lane];
                acc.x += wb * nv.x;
                acc.y += wb * nv.y;
            }
        }
    }
    float2* out2 = (float2*)out1;
    out2[(size_t)row * 64 + lane] = acc;
}

// ---------------- K5: in-place out = out1 @ W  (32 rows per block) ----------------
__global__ __launch_bounds__(256) void k_wmul(float* __restrict__ out,
                                              const float* __restrict__ W) {
    __shared__ float tile[32][FIN];
    int t = threadIdx.x;
    size_t row0 = (size_t)blockIdx.x * 32;
    float* base = out + row0 * FIN;
#pragma unroll
    for (int k = 0; k < 16; k++) {
        int idx = k * 256 + t;
        tile[idx >> 7][idx & 127] = base[idx];
    }
    __syncthreads();
    int f = t & 127;
    int h = t >> 7;
    float acc[16];
#pragma unroll
    for (int j = 0; j < 16; j++) acc[j] = 0.f;
    for (int k = 0; k < 128; k += 2) {
        float w0 = W[k * 128 + f];
        float w1 = W[(k + 1) * 128 + f];
#pragma unroll
        for (int j = 0; j < 16; j++) {
            float2 tv = *(const float2*)&tile[h * 16 + j][k];
            acc[j] += tv.x * w0 + tv.y * w1;
        }
    }
#pragma unroll
    for (int j = 0; j < 16; j++) base[(size_t)(h * 16 + j) * 128 + f] = acc[j];
}

extern "C" void kernel_launch(void* const* d_in, const int* in_sizes, int n_in,
                              void* d_out, int out_size, void* d_ws, size_t ws_size,
                              hipStream_t stream) {
    const float* node     = (const float*)d_in[0];
    const float* edge     = (const float*)d_in[1];
    const float* node_adj = (const float*)d_in[2];
    const float* D        = (const float*)d_in[3];
    const float* T        = (const float*)d_in[4];
    const float* ew       = (const float*)d_in[5];
    const float* W        = (const float*)d_in[6];
    float* out = (float*)d_out;

    // workspace layout (~1.2 MB total)
    float* hepe = (float*)d_ws;                 // B*E floats   (16 KB)
    float* dinv = hepe + BB * EE;               // B*N floats   (64 KB)
    u16*   lists = (u16*)(dinv + BB * NN);      // B*N*LSTRIDE u16 (~1.1 MB)

    k_hepe <<<BB * EE / 4,   256, 0, stream>>>(edge, ew, hepe);
    k_dinv <<<BB * NN / 256, 256, 0, stream>>>(D, dinv);
    k_lists<<<BB * NN / 4,   256, 0, stream>>>(T, lists);
    k_main <<<BB * NN / 4,   256, 0, stream>>>(node_adj, node, hepe, dinv, lists, out);
    k_wmul <<<BB * NN / 32,  256, 0, stream>>>(out, W);
}

// Round 2
// 70.731 us; speedup vs baseline: 3.4627x; 3.4627x over previous
//
#include <hip/hip_runtime.h>

#define BB 4
#define NN 4096
#define EE 1024
#define FIN 128
#define FOUT 128
#define FE 64
#define CAP 33        // max edges per node (Poisson mean 2.05 -> P(>=33) ~ 0)
#define LSTRIDE 34
#define CAPE 40       // max nodes per edge (Poisson mean 8.2 -> P(>=40) ~ 1e-16)

typedef unsigned short u16;
typedef unsigned long long u64;

// ---------------- K1: HePe[b,e] = dot(edge[b,e,:], edge_weight); also zero ecnt ----------------
__global__ __launch_bounds__(256) void k_hepe(const float* __restrict__ edge,
                                              const float* __restrict__ ew,
                                              float* __restrict__ hepe,
                                              int* __restrict__ ecnt) {
    int lane = threadIdx.x & 63;
    int wid  = threadIdx.x >> 6;
    int row  = blockIdx.x * 4 + wid;            // b*E + e
    float v = edge[(size_t)row * FE + lane] * ew[lane];
#pragma unroll
    for (int d = 32; d >= 1; d >>= 1) v += __shfl_xor(v, d, 64);
    if (lane == 0) { hepe[row] = v; ecnt[row] = 0; }
}

// ---------------- K2: dinv[b,n] = 1/sqrt(D[b,n,n]) ----------------
__global__ __launch_bounds__(256) void k_dinv(const float* __restrict__ D,
                                              float* __restrict__ dinv) {
    int t = blockIdx.x * 256 + threadIdx.x;     // b*N + n
    int b = t >> 12, n = t & (NN - 1);
    float v = D[((size_t)b * NN + n) * NN + n];
    dinv[t] = (v != 0.0f) ? (1.0f / sqrtf(v)) : 0.0f;
}

// ---------------- K3: per-node edge list from T (order within row = edge index order) ----------------
__global__ __launch_bounds__(256) void k_lists(const float* __restrict__ T,
                                               u16* __restrict__ lists) {
    int lane = threadIdx.x & 63;
    int wid  = threadIdx.x >> 6;
    int row  = blockIdx.x * 4 + wid;            // b*N + n
    const float4* rowT = (const float4*)(T + (size_t)row * EE);
    u16* L = lists + (size_t)row * LSTRIDE;
    int base = 0;
#pragma unroll
    for (int i = 0; i < 4; i++) {
        float4 tv = rowT[i * 64 + lane];
        float vs[4] = {tv.x, tv.y, tv.z, tv.w};
        int c = (tv.x != 0.f) + (tv.y != 0.f) + (tv.z != 0.f) + (tv.w != 0.f);
        int x = c;
#pragma unroll
        for (int d = 1; d < 64; d <<= 1) {
            int o = __shfl_up(x, d, 64);
            if (lane >= d) x += o;
        }
        int tot = __shfl(x, 63, 64);
        int pos = base + x - c;
#pragma unroll
        for (int s = 0; s < 4; s++) {
            if (vs[s] != 0.f) {
                if (pos < CAP) L[1 + pos] = (u16)((i * 64 + lane) * 4 + s);
                pos++;
            }
        }
        base += tot;
    }
    if (lane == 0) L[0] = (u16)(base < CAP ? base : CAP);
}

// ---------------- K3b: scatter -> per-edge node lists ----------------
__global__ __launch_bounds__(256) void k_elists(const u16* __restrict__ lists,
                                                int* __restrict__ ecnt,
                                                u16* __restrict__ elists) {
    int lane = threadIdx.x & 63;
    int wid  = threadIdx.x >> 6;
    int row  = blockIdx.x * 4 + wid;            // b*N + n
    int b = row >> 12, n = row & (NN - 1);
    const u16* L = lists + (size_t)row * LSTRIDE;
    int cn = L[0];
    if (lane < cn) {
        int e = L[1 + lane];
        int eb = (b << 10) + e;
        int pos = atomicAdd(&ecnt[eb], 1);
        if (pos < CAPE) elists[(size_t)eb * CAPE + pos] = (u16)n;
    }
}

// ---------------- K4: GEMM dst = src @ W  (32 rows per block; in-place safe) ----------------
__global__ __launch_bounds__(256) void k_gemm(const float* __restrict__ src,
                                              const float* __restrict__ W,
                                              float* __restrict__ dst) {
    __shared__ float tile[32][FIN];
    int t = threadIdx.x;
    size_t row0 = (size_t)blockIdx.x * 32;
    const float* sbase = src + row0 * FIN;
    float* dbase = dst + row0 * FIN;
#pragma unroll
    for (int k = 0; k < 16; k++) {
        int idx = k * 256 + t;
        tile[idx >> 7][idx & 127] = sbase[idx];
    }
    __syncthreads();
    int f = t & 127;
    int h = t >> 7;
    float acc[16];
#pragma unroll
    for (int j = 0; j < 16; j++) acc[j] = 0.f;
    for (int k = 0; k < 128; k += 2) {
        float w0 = W[k * 128 + f];
        float w1 = W[(k + 1) * 128 + f];
#pragma unroll
        for (int j = 0; j < 16; j++) {
            float2 tv = *(const float2*)&tile[h * 16 + j][k];
            acc[j] += tv.x * w0 + tv.y * w1;
        }
    }
#pragma unroll
    for (int j = 0; j < 16; j++) dbase[(size_t)(h * 16 + j) * 128 + f] = acc[j];
}

// ---------------- K5: out[b,n,:] = sum over (e in edges(n), m in nodes(e)) of
//                      h[e] * (A[n,m]+delta_nm) * dinv[m] * rows[m,:]  ----------------
__global__ __launch_bounds__(256) void k_main(const float* __restrict__ A,
                                              const float* __restrict__ rows,
                                              const float* __restrict__ hepe,
                                              const float* __restrict__ dinv,
                                              const u16* __restrict__ lists,
                                              const int* __restrict__ ecnt,
                                              const u16* __restrict__ elists,
                                              float* __restrict__ out) {
    int lane = threadIdx.x & 63;
    int wid  = threadIdx.x >> 6;
    int row  = blockIdx.x * 4 + wid;            // b*N + n
    int b = row >> 12, n = row & (NN - 1);

    const u16* L = lists + (size_t)row * LSTRIDE;
    int cn = L[0];
    int eReg = 0; float hReg = 0.f;
    if (lane < cn) {
        eReg = L[1 + lane];
        hReg = hepe[(b << 10) + eReg];
    }

    const float2* rows2 = (const float2*)rows;
    float2 acc = make_float2(0.f, 0.f);

    for (int j = 0; j < cn; j++) {
        int   e = __shfl(eReg, j, 64);
        float h = __shfl(hReg, j, 64);
        int eb = (b << 10) + e;
        int cm = ecnt[eb];
        if (cm > CAPE) cm = CAPE;
        float c = 0.f; int m = 0;
        if (lane < cm) {
            m = elists[(size_t)eb * CAPE + lane];
            float a = A[((size_t)b << 24) + ((size_t)n << 12) + m];
            if (m == n) a += 1.0f;              // A = node_adj + I
            if (a != 0.f) c = h * a * dinv[(b << 12) + m];
        }
        u64 mask = __ballot(c != 0.f);
        while (mask) {
            int src = __ffsll(mask) - 1;
            mask &= mask - 1;
            float cb = __shfl(c, src, 64);
            int   mb = __shfl(m, src, 64);
            float2 nv = rows2[((size_t)((b << 12) + mb)) * 64 + lane];
            acc.x += cb * nv.x;
            acc.y += cb * nv.y;
        }
    }
    float2* out2 = (float2*)out;
    out2[(size_t)row * 64 + lane] = acc;
}

extern "C" void kernel_launch(void* const* d_in, const int* in_sizes, int n_in,
                              void* d_out, int out_size, void* d_ws, size_t ws_size,
                              hipStream_t stream) {
    const float* node     = (const float*)d_in[0];
    const float* edge     = (const float*)d_in[1];
    const float* node_adj = (const float*)d_in[2];
    const float* D        = (const float*)d_in[3];
    const float* T        = (const float*)d_in[4];
    const float* ew       = (const float*)d_in[5];
    const float* W        = (const float*)d_in[6];
    float* out = (float*)d_out;

    // workspace layout
    char* ws = (char*)d_ws;
    float* hepe  = (float*)ws;                          ws += BB * EE * 4;          // 16 KB
    float* dinv  = (float*)ws;                          ws += BB * NN * 4;          // 64 KB
    int*   ecnt  = (int*)ws;                            ws += BB * EE * 4;          // 16 KB
    u16*   lists = (u16*)ws;                            ws += BB * NN * LSTRIDE * 2;// ~1.1 MB
    u16*   elists= (u16*)ws;                            ws += BB * EE * CAPE * 2;   // 320 KB
    size_t small_need = (size_t)(ws - (char*)d_ws);
    float* nodeW = (float*)ws;                          // 8.39 MB (optional)
    bool fuse = ws_size >= small_need + (size_t)BB * NN * FIN * 4;

    k_hepe  <<<BB * EE / 4,   256, 0, stream>>>(edge, ew, hepe, ecnt);
    k_dinv  <<<BB * NN / 256, 256, 0, stream>>>(D, dinv);
    k_lists <<<BB * NN / 4,   256, 0, stream>>>(T, lists);
    k_elists<<<BB * NN / 4,   256, 0, stream>>>(lists, ecnt, elists);

    if (fuse) {
        // nodeW = node @ W up front; main kernel emits final output directly.
        k_gemm <<<BB * NN / 32, 256, 0, stream>>>(node, W, nodeW);
        k_main <<<BB * NN / 4,  256, 0, stream>>>(node_adj, nodeW, hepe, dinv,
                                                  lists, ecnt, elists, out);
    } else {
        // fallback: out1 into d_out, then in-place @W
        k_main <<<BB * NN / 4,  256, 0, stream>>>(node_adj, node, hepe, dinv,
                                                  lists, ecnt, elists, out);
        k_gemm <<<BB * NN / 32, 256, 0, stream>>>(out, W, out);
    }
}